// Round 3
// baseline (313.614 us; speedup 1.0000x reference)
//
#include <hip/hip_runtime.h>
#include <hip/hip_bf16.h>

typedef __bf16 bf16_t;
typedef __attribute__((ext_vector_type(8))) __bf16 bf16x8;
typedef __attribute__((ext_vector_type(4))) float f32x4;

#define EPSF 1e-5f

// ---------------------------------------------------------------------------
// GEMM: C[n][j] = sum_k Hd[n][k] * W[j][k]   n in [0,32), j in [0,M), k in [0,K)
// Inputs fp32, converted to bf16 fragments on the fly; fp32 MFMA accumulate.
// MFMA 16x16x32 bf16. Block = 256 thr = 4 waves; each wave one k-quarter.
// Grid = (M/16)*2 blocks.
// A-frag: lane holds A[m=lane&15][k=quad*8+j]
// B-frag: lane holds B[k=quad*8+j][n=lane&15]
// D: lane L reg r -> row=(L>>4)*4+r, col=L&15
// ---------------------------------------------------------------------------
__global__ __launch_bounds__(256) void gemm32_mfma(
    const float* __restrict__ Hd, const float* __restrict__ W,
    float* __restrict__ C, int M, int K, int wstride, int jtiles)
{
    int bx   = blockIdx.x;
    int jt   = bx % jtiles;
    int nt   = bx / jtiles;
    int tid  = threadIdx.x;
    int wave = tid >> 6;
    int lane = tid & 63;
    int l15  = lane & 15;
    int quad = lane >> 4;
    int kper = K >> 2;
    int k0   = wave * kper;

    const float* ap = Hd + (size_t)(nt * 16 + l15) * 2048 + quad * 8 + k0;
    const float* bp = W  + (size_t)(jt * 16 + l15) * wstride + quad * 8 + k0;

    f32x4 acc = {0.f, 0.f, 0.f, 0.f};
    for (int k = 0; k < kper; k += 32) {
        float4 a0 = *(const float4*)(ap + k);
        float4 a1 = *(const float4*)(ap + k + 4);
        float4 b0 = *(const float4*)(bp + k);
        float4 b1 = *(const float4*)(bp + k + 4);
        bf16x8 av, bv;
        av[0] = (bf16_t)a0.x; av[1] = (bf16_t)a0.y; av[2] = (bf16_t)a0.z; av[3] = (bf16_t)a0.w;
        av[4] = (bf16_t)a1.x; av[5] = (bf16_t)a1.y; av[6] = (bf16_t)a1.z; av[7] = (bf16_t)a1.w;
        bv[0] = (bf16_t)b0.x; bv[1] = (bf16_t)b0.y; bv[2] = (bf16_t)b0.z; bv[3] = (bf16_t)b0.w;
        bv[4] = (bf16_t)b1.x; bv[5] = (bf16_t)b1.y; bv[6] = (bf16_t)b1.z; bv[7] = (bf16_t)b1.w;
        acc = __builtin_amdgcn_mfma_f32_16x16x32_bf16(av, bv, acc, 0, 0, 0);
    }

    __shared__ float red[4][16][16];
    #pragma unroll
    for (int r = 0; r < 4; ++r) red[wave][quad * 4 + r][l15] = acc[r];
    __syncthreads();

    int row = tid >> 4, col = tid & 15;
    float s = red[0][row][col] + red[1][row][col] + red[2][row][col] + red[3][row][col];
    C[(size_t)(nt * 16 + row) * M + jt * 16 + col] = s;
}

// ---------------------------------------------------------------------------
// GEMV: out[row] = sum_k W[row][k] * x[k].  One wave per row, 4 rows / block.
// fp32, float4 loads. Grid = M/4 blocks of 256.
// ---------------------------------------------------------------------------
__global__ __launch_bounds__(256) void gemv_k(
    const float* __restrict__ W, const float* __restrict__ x,
    float* __restrict__ out, int K, int wstride)
{
    int row  = blockIdx.x * 4 + (threadIdx.x >> 6);
    int lane = threadIdx.x & 63;
    const float4* wp = (const float4*)(W + (size_t)row * wstride) + lane;
    const float4* xp = (const float4*)x + lane;
    int kq = K >> 2;
    float acc = 0.f;
    for (int k = 0; k < kq; k += 64) {
        float4 w = wp[k];
        float4 v = xp[k];
        acc += w.x * v.x + w.y * v.y + w.z * v.z + w.w * v.w;
    }
    #pragma unroll
    for (int off = 32; off; off >>= 1) acc += __shfl_down(acc, off, 64);
    if (lane == 0) out[row] = acc;
}

// ---------------------------------------------------------------------------
// Attention logit partials: lp[b*32+n] = sum_{j in 64-slice b} tanh(ai[n][j]+ej[j])*wattn[j]
// Grid = 32 blocks x 256 thr (4 waves x 8 n each).
// ---------------------------------------------------------------------------
__global__ __launch_bounds__(256) void attn_part(
    const float* __restrict__ ai, const float* __restrict__ ej,
    const float* __restrict__ wattn, float* __restrict__ lp)
{
    int b    = blockIdx.x;
    int wave = threadIdx.x >> 6;
    int lane = threadIdx.x & 63;
    int j    = b * 64 + lane;
    float e  = ej[j];
    float wa = wattn[j];
    #pragma unroll
    for (int i = 0; i < 8; ++i) {
        int n = wave * 8 + i;
        float v = tanhf(ai[n * 2048 + j] + e) * wa;
        #pragma unroll
        for (int off = 32; off; off >>= 1) v += __shfl_down(v, off, 64);
        if (lane == 0) lp[b * 32 + n] = v;
    }
}

// Reduce partials + softmax over N=32. One wave.
__global__ __launch_bounds__(64) void attn_fin(
    const float* __restrict__ lp, float* __restrict__ attn)
{
    int lane = threadIdx.x;
    float logit = -1e30f;
    if (lane < 32) {
        float s = 0.f;
        for (int b = 0; b < 32; ++b) s += lp[b * 32 + lane];
        logit = s;
    }
    float m = logit;
    #pragma unroll
    for (int off = 32; off; off >>= 1) m = fmaxf(m, __shfl_xor(m, off, 64));
    float e = (lane < 32) ? expf(logit - m) : 0.f;
    float s = e;
    #pragma unroll
    for (int off = 32; off; off >>= 1) s += __shfl_xor(s, off, 64);
    if (lane < 32) attn[lane] = e / s;
}

// merged[h] = sum_n attn[n] * hiddens[n][h]. Grid 8 x 256.
__global__ __launch_bounds__(256) void merge_k(
    const float* __restrict__ attn, const float* __restrict__ hiddens,
    float* __restrict__ merged)
{
    int h = blockIdx.x * 256 + threadIdx.x;
    float acc = 0.f;
    #pragma unroll 8
    for (int n = 0; n < 32; ++n) acc += attn[n] * hiddens[n * 2048 + h];
    merged[h] = acc;
}

// tanh(LN(mm)*g+b) -> xcat[2048:], input -> xcat[0:2048]. One block of 256.
__global__ __launch_bounds__(256) void ln_cat(
    const float* __restrict__ mm, const float* __restrict__ g, const float* __restrict__ b,
    const float* __restrict__ input, float* __restrict__ xcat)
{
    __shared__ float s1[256], s2[256];
    int t = threadIdx.x;
    float v[8]; float sum = 0.f, sq = 0.f;
    #pragma unroll
    for (int i = 0; i < 8; ++i) {
        v[i] = mm[t * 8 + i]; sum += v[i]; sq += v[i] * v[i];
    }
    s1[t] = sum; s2[t] = sq;
    __syncthreads();
    for (int off = 128; off; off >>= 1) {
        if (t < off) { s1[t] += s1[t + off]; s2[t] += s2[t + off]; }
        __syncthreads();
    }
    const float inv = 1.f / 2048.f;
    float mean = s1[0] * inv;
    float r = rsqrtf(s2[0] * inv - mean * mean + EPSF);
    #pragma unroll
    for (int i = 0; i < 8; ++i) {
        int h = t * 8 + i;
        xcat[2048 + h] = tanhf((v[i] - mean) * r * g[h] + b[h]);
        xcat[h] = input[h];
    }
}

// Per-row mean/rstd of f_lin[n][h] = fi[h] + fh[n][h]. Grid 32 x 256.
__global__ __launch_bounds__(256) void f_stats(
    const float* __restrict__ fi, const float* __restrict__ fh, float* __restrict__ frs)
{
    __shared__ float s1[256], s2[256];
    int n = blockIdx.x, t = threadIdx.x;
    float sum = 0.f, sq = 0.f;
    #pragma unroll
    for (int i = 0; i < 8; ++i) {
        int h = t * 8 + i;
        float v = fi[h] + fh[n * 2048 + h];
        sum += v; sq += v * v;
    }
    s1[t] = sum; s2[t] = sq;
    __syncthreads();
    for (int off = 128; off; off >>= 1) {
        if (t < off) { s1[t] += s1[t + off]; s2[t] += s2[t + off]; }
        __syncthreads();
    }
    if (t == 0) {
        const float inv = 1.f / 2048.f;
        float mean = s1[0] * inv;
        float var  = s2[0] * inv - mean * mean;
        frs[n * 2]     = mean;
        frs[n * 2 + 1] = rsqrtf(var + EPSF);
    }
}

// fc[h] = sum_n sigmoid((fi[h]+fh[n][h]-m_n)*r_n*g[h]+b[h]) * cells[n][h]. Grid 8 x 256.
__global__ __launch_bounds__(256) void fc_sum(
    const float* __restrict__ fi, const float* __restrict__ fh, const float* __restrict__ frs,
    const float* __restrict__ gf, const float* __restrict__ bf_,
    const float* __restrict__ cells, float* __restrict__ fc)
{
    int h = blockIdx.x * 256 + threadIdx.x;
    float g = gf[h], bb = bf_[h], f_i = fi[h];
    float acc = 0.f;
    for (int n = 0; n < 32; ++n) {
        float v = (f_i + fh[n * 2048 + h] - frs[n * 2]) * frs[n * 2 + 1] * g + bb;
        float f = 1.f / (1.f + expf(-v));
        acc += f * cells[n * 2048 + h];
    }
    fc[h] = acc;
}

// Fused tail: i/o/u LN stats + gates, v = i*u+fc, LN(v), fp32 outputs. One block 256.
__global__ __launch_bounds__(256) void tail_k(
    const float* __restrict__ iou, const float* __restrict__ fc,
    const float* __restrict__ gi, const float* __restrict__ bi,
    const float* __restrict__ go, const float* __restrict__ bo,
    const float* __restrict__ gu, const float* __restrict__ bu,
    const float* __restrict__ gc, const float* __restrict__ bc,
    float* __restrict__ out)
{
    __shared__ float sA[6][256];
    int t = threadIdx.x;
    float vi[8], vo[8], vu[8];
    float si = 0, qi = 0, so = 0, qo = 0, su = 0, qu = 0;
    #pragma unroll
    for (int i = 0; i < 8; ++i) {
        int h = t * 8 + i;
        vi[i] = iou[h]; vo[i] = iou[2048 + h]; vu[i] = iou[4096 + h];
        si += vi[i]; qi += vi[i] * vi[i];
        so += vo[i]; qo += vo[i] * vo[i];
        su += vu[i]; qu += vu[i] * vu[i];
    }
    sA[0][t] = si; sA[1][t] = qi; sA[2][t] = so;
    sA[3][t] = qo; sA[4][t] = su; sA[5][t] = qu;
    __syncthreads();
    for (int off = 128; off; off >>= 1) {
        if (t < off) {
            #pragma unroll
            for (int c = 0; c < 6; ++c) sA[c][t] += sA[c][t + off];
        }
        __syncthreads();
    }
    const float inv = 1.f / 2048.f;
    float mi = sA[0][0] * inv, ri = rsqrtf(sA[1][0] * inv - mi * mi + EPSF);
    float mo = sA[2][0] * inv, ro = rsqrtf(sA[3][0] * inv - mo * mo + EPSF);
    float mu = sA[4][0] * inv, ru = rsqrtf(sA[5][0] * inv - mu * mu + EPSF);
    __syncthreads();

    float o_[8], v_[8];
    float sv = 0, qv = 0;
    #pragma unroll
    for (int i = 0; i < 8; ++i) {
        int h = t * 8 + i;
        float ivl = 1.f / (1.f + expf(-((vi[i] - mi) * ri * gi[h] + bi[h])));
        o_[i]     = 1.f / (1.f + expf(-((vo[i] - mo) * ro * go[h] + bo[h])));
        float uvl = tanhf((vu[i] - mu) * ru * gu[h] + bu[h]);
        v_[i] = ivl * uvl + fc[h];
        sv += v_[i]; qv += v_[i] * v_[i];
    }
    sA[0][t] = sv; sA[1][t] = qv;
    __syncthreads();
    for (int off = 128; off; off >>= 1) {
        if (t < off) { sA[0][t] += sA[0][t + off]; sA[1][t] += sA[1][t + off]; }
        __syncthreads();
    }
    float mc = sA[0][0] * inv, rc = rsqrtf(sA[1][0] * inv - mc * mc + EPSF);
    #pragma unroll
    for (int i = 0; i < 8; ++i) {
        int h = t * 8 + i;
        float nc = (v_[i] - mc) * rc * gc[h] + bc[h];
        float nh = o_[i] * tanhf(nc);
        out[h]        = nh;   // new_h
        out[2048 + h] = nc;   // new_cell
    }
}

// ---------------------------------------------------------------------------
extern "C" void kernel_launch(void* const* d_in, const int* in_sizes, int n_in,
                              void* d_out, int out_size, void* d_ws, size_t ws_size,
                              hipStream_t stream)
{
    const float* input    = (const float*)d_in[0];   // [2048]
    const float* hiddens  = (const float*)d_in[1];   // [32,2048]
    const float* cells    = (const float*)d_in[2];   // [32,2048]
    const float* external = (const float*)d_in[3];   // [2048]
    const float* W_ai     = (const float*)d_in[4];   // [2048,4096]
    const float* W_attn   = (const float*)d_in[5];   // [1,2048]
    const float* W_merge  = (const float*)d_in[6];   // [2048,2048]
    const float* W_iou    = (const float*)d_in[7];   // [6144,4096]
    const float* W_fi     = (const float*)d_in[8];   // [2048,2048]
    const float* W_fh     = (const float*)d_in[9];   // [2048,2048]
    const float* g_merge  = (const float*)d_in[10];
    const float* b_merge  = (const float*)d_in[11];
    const float* g_f      = (const float*)d_in[12];
    const float* b_f      = (const float*)d_in[13];
    const float* g_i      = (const float*)d_in[14];
    const float* b_i      = (const float*)d_in[15];
    const float* g_o      = (const float*)d_in[16];
    const float* b_o      = (const float*)d_in[17];
    const float* g_u      = (const float*)d_in[18];
    const float* b_u      = (const float*)d_in[19];
    const float* g_c      = (const float*)d_in[20];
    const float* b_c      = (const float*)d_in[21];

    float* ws = (float*)d_ws;
    float* ws_ai     = ws;              // 32*2048
    float* ws_fh     = ws + 65536;      // 32*2048
    float* ws_ej     = ws + 131072;     // 2048
    float* ws_fi     = ws + 133120;     // 2048
    float* ws_lp     = ws + 135168;     // 32*32
    float* ws_attn   = ws + 136192;     // 32
    float* ws_mm     = ws + 136224;     // 2048
    float* ws_fc     = ws + 138272;     // 2048
    float* ws_iou    = ws + 140320;     // 6144
    float* ws_frs    = ws + 146464;     // 64
    float* ws_merged = ws + 146528;     // 2048
    float* ws_xcat   = ws + 148576;     // 4096
    float* out = (float*)d_out;

    // Input-only GEMMs / GEMVs
    gemm32_mfma<<<256, 256, 0, stream>>>(hiddens, W_ai, ws_ai, 2048, 2048, 4096, 128);
    gemm32_mfma<<<256, 256, 0, stream>>>(hiddens, W_fh, ws_fh, 2048, 2048, 2048, 128);
    gemv_k<<<512, 256, 0, stream>>>(W_ai + 2048, external, ws_ej, 2048, 4096);
    gemv_k<<<512, 256, 0, stream>>>(W_fi, input, ws_fi, 2048, 2048);

    // Attention path
    attn_part<<<32, 256, 0, stream>>>(ws_ai, ws_ej, W_attn, ws_lp);
    attn_fin<<<1, 64, 0, stream>>>(ws_lp, ws_attn);
    merge_k<<<8, 256, 0, stream>>>(ws_attn, hiddens, ws_merged);
    gemv_k<<<512, 256, 0, stream>>>(W_merge, ws_merged, ws_mm, 2048, 2048);
    ln_cat<<<1, 256, 0, stream>>>(ws_mm, g_merge, b_merge, input, ws_xcat);
    gemv_k<<<1536, 256, 0, stream>>>(W_iou, ws_xcat, ws_iou, 4096, 4096);

    // Forget path
    f_stats<<<32, 256, 0, stream>>>(ws_fi, ws_fh, ws_frs);
    fc_sum<<<8, 256, 0, stream>>>(ws_fi, ws_fh, ws_frs, g_f, b_f, cells, ws_fc);

    // Fused tail
    tail_k<<<1, 256, 0, stream>>>(ws_iou, ws_fc, g_i, b_i, g_o, b_o,
                                  g_u, b_u, g_c, b_c, out);
}

// Round 4
// 279.721 us; speedup vs baseline: 1.1212x; 1.1212x over previous
//
#include <hip/hip_runtime.h>
#include <hip/hip_bf16.h>

typedef __bf16 bf16_t;
typedef __attribute__((ext_vector_type(8))) __bf16 bf16x8;
typedef __attribute__((ext_vector_type(4))) float f32x4;

#define EPSF 1e-5f

// ===========================================================================
// S1 mega-kernel. Grid 640 x 256:
//   blocks [0,256):   gemm_ai  (hiddens @ W_ai[:, :2048].T) + folded ej GEMV
//                     (W_ai[:, 2048:] @ external) + fused attention-logit
//                     epilogue -> lp[jt*32 + n] partials (128 x 32)
//   blocks [256,512): gemm_fh  (hiddens @ W_fh.T) -> ws_fh[n][j]
//   blocks [512,640): gemv_fi  (W_fi @ input)     -> ws_fi[2048]
// MFMA 16x16x32 bf16, fp32 accumulate. 4 waves, each one K-quarter.
// A-frag: lane holds A[m=lane&15][k=quad*8+j]; B-frag: B[k][n=lane&15]
// D: lane L reg r -> row=(L>>4)*4+r, col=L&15
// ===========================================================================
__global__ __launch_bounds__(256) void s1_mega(
    const float* __restrict__ hiddens, const float* __restrict__ external,
    const float* __restrict__ input,
    const float* __restrict__ W_ai, const float* __restrict__ W_fh,
    const float* __restrict__ W_fi, const float* __restrict__ W_attn,
    float* __restrict__ lp, float* __restrict__ fh_out, float* __restrict__ fi_out)
{
    __shared__ float red[4][16][16];
    __shared__ float ejs[4][16];

    int b    = blockIdx.x;
    int tid  = threadIdx.x;
    int wave = tid >> 6;
    int lane = tid & 63;

    if (b < 512) {
        // ---------------- GEMM branch ----------------
        bool is_ai = (b < 256);
        int  bb    = is_ai ? b : b - 256;
        int  jt    = bb & 127;
        int  nt    = bb >> 7;
        int  l15   = lane & 15;
        int  quad  = lane >> 4;
        int  k0    = wave * 512;                  // K=2048, kper=512
        int  wstride = is_ai ? 4096 : 2048;
        const float* W = is_ai ? W_ai : W_fh;

        const float* ap = hiddens + (size_t)(nt * 16 + l15) * 2048 + quad * 8 + k0;
        const float* bp = W + (size_t)(jt * 16 + l15) * wstride + quad * 8 + k0;

        f32x4 acc = {0.f, 0.f, 0.f, 0.f};
        float ejacc = 0.f;

        if (is_ai) {
            const float* ep = bp + 2048;          // W_ai[row][2048 + ...]
            const float* xp = external + quad * 8 + k0;
            for (int k = 0; k < 512; k += 32) {
                float4 a0 = *(const float4*)(ap + k);
                float4 a1 = *(const float4*)(ap + k + 4);
                float4 b0 = *(const float4*)(bp + k);
                float4 b1 = *(const float4*)(bp + k + 4);
                bf16x8 av, bv;
                av[0]=(bf16_t)a0.x; av[1]=(bf16_t)a0.y; av[2]=(bf16_t)a0.z; av[3]=(bf16_t)a0.w;
                av[4]=(bf16_t)a1.x; av[5]=(bf16_t)a1.y; av[6]=(bf16_t)a1.z; av[7]=(bf16_t)a1.w;
                bv[0]=(bf16_t)b0.x; bv[1]=(bf16_t)b0.y; bv[2]=(bf16_t)b0.z; bv[3]=(bf16_t)b0.w;
                bv[4]=(bf16_t)b1.x; bv[5]=(bf16_t)b1.y; bv[6]=(bf16_t)b1.z; bv[7]=(bf16_t)b1.w;
                acc = __builtin_amdgcn_mfma_f32_16x16x32_bf16(av, bv, acc, 0, 0, 0);
                float4 e0 = *(const float4*)(ep + k);
                float4 e1 = *(const float4*)(ep + k + 4);
                float4 x0 = *(const float4*)(xp + k);
                float4 x1 = *(const float4*)(xp + k + 4);
                ejacc += e0.x*x0.x + e0.y*x0.y + e0.z*x0.z + e0.w*x0.w
                       + e1.x*x1.x + e1.y*x1.y + e1.z*x1.z + e1.w*x1.w;
            }
            // reduce ej over the 4 quads sharing l15
            ejacc += __shfl_xor(ejacc, 16, 64);
            ejacc += __shfl_xor(ejacc, 32, 64);
            if (quad == 0) ejs[wave][l15] = ejacc;
        } else {
            for (int k = 0; k < 512; k += 32) {
                float4 a0 = *(const float4*)(ap + k);
                float4 a1 = *(const float4*)(ap + k + 4);
                float4 b0 = *(const float4*)(bp + k);
                float4 b1 = *(const float4*)(bp + k + 4);
                bf16x8 av, bv;
                av[0]=(bf16_t)a0.x; av[1]=(bf16_t)a0.y; av[2]=(bf16_t)a0.z; av[3]=(bf16_t)a0.w;
                av[4]=(bf16_t)a1.x; av[5]=(bf16_t)a1.y; av[6]=(bf16_t)a1.z; av[7]=(bf16_t)a1.w;
                bv[0]=(bf16_t)b0.x; bv[1]=(bf16_t)b0.y; bv[2]=(bf16_t)b0.z; bv[3]=(bf16_t)b0.w;
                bv[4]=(bf16_t)b1.x; bv[5]=(bf16_t)b1.y; bv[6]=(bf16_t)b1.z; bv[7]=(bf16_t)b1.w;
                acc = __builtin_amdgcn_mfma_f32_16x16x32_bf16(av, bv, acc, 0, 0, 0);
            }
        }

        #pragma unroll
        for (int r = 0; r < 4; ++r) red[wave][quad * 4 + r][l15] = acc[r];
        __syncthreads();

        int row = tid >> 4, col = tid & 15;
        float s = red[0][row][col] + red[1][row][col] + red[2][row][col] + red[3][row][col];

        if (is_ai) {
            float ej = ejs[0][col] + ejs[1][col] + ejs[2][col] + ejs[3][col];
            float lg = tanhf(s + ej) * W_attn[jt * 16 + col];
            // reduce over the 16 cols within each row group (16 consecutive threads)
            lg += __shfl_xor(lg, 1, 64);
            lg += __shfl_xor(lg, 2, 64);
            lg += __shfl_xor(lg, 4, 64);
            lg += __shfl_xor(lg, 8, 64);
            if (col == 0) lp[jt * 32 + nt * 16 + row] = lg;
        } else {
            fh_out[(size_t)(nt * 16 + row) * 2048 + jt * 16 + col] = s;
        }
    } else {
        // ---------------- gemv_fi branch: 128 blocks, 16 rows each ----------
        int b2 = b - 512;
        #pragma unroll
        for (int r = 0; r < 4; ++r) {
            int row = b2 * 16 + wave * 4 + r;
            const float4* wp = (const float4*)(W_fi + (size_t)row * 2048) + lane;
            const float4* xp = (const float4*)input + lane;
            float acc2 = 0.f;
            #pragma unroll
            for (int k = 0; k < 512; k += 64) {
                float4 w = wp[k];
                float4 v = xp[k];
                acc2 += w.x*v.x + w.y*v.y + w.z*v.z + w.w*v.w;
            }
            #pragma unroll
            for (int off = 32; off; off >>= 1) acc2 += __shfl_down(acc2, off, 64);
            if (lane == 0) fi_out[row] = acc2;
        }
    }
}

// ===========================================================================
// S2 mega-kernel. Grid 40 x 256:
//   blocks [0,32):  per-child LN stats of f_lin[n] = fi + fh[n] -> frs[n]
//   blocks [32,40): reduce lp partials -> softmax over 32 (redundant per
//                   block) -> merged[h] slice
// ===========================================================================
__global__ __launch_bounds__(256) void s2_mega(
    const float* __restrict__ fi, const float* __restrict__ fh,
    const float* __restrict__ lp, const float* __restrict__ hiddens,
    float* __restrict__ frs, float* __restrict__ merged)
{
    __shared__ float s1[256], s2[256];
    int b = blockIdx.x, t = threadIdx.x;

    if (b < 32) {
        int n = b;
        float sum = 0.f, sq = 0.f;
        #pragma unroll
        for (int i = 0; i < 8; ++i) {
            int h = t * 8 + i;
            float v = fi[h] + fh[n * 2048 + h];
            sum += v; sq += v * v;
        }
        s1[t] = sum; s2[t] = sq;
        __syncthreads();
        for (int off = 128; off; off >>= 1) {
            if (t < off) { s1[t] += s1[t + off]; s2[t] += s2[t + off]; }
            __syncthreads();
        }
        if (t == 0) {
            const float inv = 1.f / 2048.f;
            float mean = s1[0] * inv;
            frs[n * 2]     = mean;
            frs[n * 2 + 1] = rsqrtf(s2[0] * inv - mean * mean + EPSF);
        }
    } else {
        // logits: sum 128 partials per n.  t -> n = t>>3, slice s = t&7 (16 each)
        __shared__ float lred[32][8];
        __shared__ float attnw[32];
        int n = t >> 3, sl = t & 7;
        float p = 0.f;
        #pragma unroll
        for (int m = 0; m < 16; ++m) p += lp[(sl * 16 + m) * 32 + n];
        lred[n][sl] = p;
        __syncthreads();
        if (sl == 0) {
            float lg = 0.f;
            #pragma unroll
            for (int m = 0; m < 8; ++m) lg += lred[n][m];
            lred[n][0] = lg;
        }
        __syncthreads();
        if (t < 32) {
            // softmax over 32 (each of the 32 threads redundantly scans)
            float mx = -1e30f;
            for (int m = 0; m < 32; ++m) mx = fmaxf(mx, lred[m][0]);
            float ssum = 0.f;
            for (int m = 0; m < 32; ++m) ssum += expf(lred[m][0] - mx);
            attnw[t] = expf(lred[t][0] - mx) / ssum;
        }
        __syncthreads();
        int h = (b - 32) * 256 + t;
        float acc = 0.f;
        #pragma unroll 8
        for (int n2 = 0; n2 < 32; ++n2) acc += attnw[n2] * hiddens[n2 * 2048 + h];
        merged[h] = acc;
    }
}

// ===========================================================================
// S3 mega-kernel. Grid 520 x 256:
//   blocks [0,512):   gemv  mm = W_merge @ merged   (4 rows / block)
//   blocks [512,520): fc[h] = sum_n sigmoid(LN_n(fi+fh)[h]*g+b) * cells[n][h]
// ===========================================================================
__global__ __launch_bounds__(256) void s3_mega(
    const float* __restrict__ W_merge, const float* __restrict__ merged,
    const float* __restrict__ fi, const float* __restrict__ fh,
    const float* __restrict__ frs, const float* __restrict__ gf,
    const float* __restrict__ bf_, const float* __restrict__ cells,
    float* __restrict__ mm, float* __restrict__ fc)
{
    int b = blockIdx.x, t = threadIdx.x;
    if (b < 512) {
        int row  = b * 4 + (t >> 6);
        int lane = t & 63;
        const float4* wp = (const float4*)(W_merge + (size_t)row * 2048) + lane;
        const float4* xp = (const float4*)merged + lane;
        float acc = 0.f;
        #pragma unroll
        for (int k = 0; k < 512; k += 64) {
            float4 w = wp[k];
            float4 v = xp[k];
            acc += w.x*v.x + w.y*v.y + w.z*v.z + w.w*v.w;
        }
        #pragma unroll
        for (int off = 32; off; off >>= 1) acc += __shfl_down(acc, off, 64);
        if (lane == 0) mm[row] = acc;
    } else {
        int h = (b - 512) * 256 + t;
        float g = gf[h], bb = bf_[h], f_i = fi[h];
        float acc = 0.f;
        for (int n = 0; n < 32; ++n) {
            float v = (f_i + fh[n * 2048 + h] - frs[n * 2]) * frs[n * 2 + 1] * g + bb;
            float f = 1.f / (1.f + expf(-v));
            acc += f * cells[n * 2048 + h];
        }
        fc[h] = acc;
    }
}

// ===========================================================================
// S4: gemv iou = W_iou @ xcat, with xcat = [input ; tanh(LN(mm)*g+b)]
// built redundantly per block into LDS. Grid 384 x 256, 16 rows / block.
// ===========================================================================
__global__ __launch_bounds__(256) void s4_iou(
    const float* __restrict__ W_iou, const float* __restrict__ mm,
    const float* __restrict__ input, const float* __restrict__ g,
    const float* __restrict__ bvec, float* __restrict__ iou)
{
    __shared__ float xcat[4096];
    __shared__ float s1[256], s2[256];
    int b = blockIdx.x, t = threadIdx.x;

    float v[8]; float sum = 0.f, sq = 0.f;
    #pragma unroll
    for (int i = 0; i < 8; ++i) {
        v[i] = mm[t * 8 + i]; sum += v[i]; sq += v[i] * v[i];
    }
    s1[t] = sum; s2[t] = sq;
    __syncthreads();
    for (int off = 128; off; off >>= 1) {
        if (t < off) { s1[t] += s1[t + off]; s2[t] += s2[t + off]; }
        __syncthreads();
    }
    const float inv = 1.f / 2048.f;
    float mean = s1[0] * inv;
    float r = rsqrtf(s2[0] * inv - mean * mean + EPSF);
    #pragma unroll
    for (int i = 0; i < 8; ++i) {
        int h = t * 8 + i;
        xcat[h]        = input[h];
        xcat[2048 + h] = tanhf((v[i] - mean) * r * g[h] + bvec[h]);
    }
    __syncthreads();

    int wave = t >> 6, lane = t & 63;
    #pragma unroll
    for (int rr = 0; rr < 4; ++rr) {
        int row = b * 16 + wave * 4 + rr;
        const float4* wp = (const float4*)(W_iou + (size_t)row * 4096) + lane;
        const float4* xp = (const float4*)xcat + lane;
        float acc = 0.f;
        #pragma unroll
        for (int k = 0; k < 1024; k += 64) {
            float4 w = wp[k];
            float4 x = xp[k];
            acc += w.x*x.x + w.y*x.y + w.z*x.z + w.w*x.w;
        }
        #pragma unroll
        for (int off = 32; off; off >>= 1) acc += __shfl_down(acc, off, 64);
        if (lane == 0) iou[row] = acc;
    }
}

// ===========================================================================
// S5: fused tail — i/o/u LN stats + gates, v = i*u + fc, LN(v), fp32 out.
// One block of 256.
// ===========================================================================
__global__ __launch_bounds__(256) void s5_tail(
    const float* __restrict__ iou, const float* __restrict__ fc,
    const float* __restrict__ gi, const float* __restrict__ bi,
    const float* __restrict__ go, const float* __restrict__ bo,
    const float* __restrict__ gu, const float* __restrict__ bu,
    const float* __restrict__ gc, const float* __restrict__ bc,
    float* __restrict__ out)
{
    __shared__ float sA[6][256];
    int t = threadIdx.x;
    float vi[8], vo[8], vu[8];
    float si = 0, qi = 0, so = 0, qo = 0, su = 0, qu = 0;
    #pragma unroll
    for (int i = 0; i < 8; ++i) {
        int h = t * 8 + i;
        vi[i] = iou[h]; vo[i] = iou[2048 + h]; vu[i] = iou[4096 + h];
        si += vi[i]; qi += vi[i] * vi[i];
        so += vo[i]; qo += vo[i] * vo[i];
        su += vu[i]; qu += vu[i] * vu[i];
    }
    sA[0][t] = si; sA[1][t] = qi; sA[2][t] = so;
    sA[3][t] = qo; sA[4][t] = su; sA[5][t] = qu;
    __syncthreads();
    for (int off = 128; off; off >>= 1) {
        if (t < off) {
            #pragma unroll
            for (int c = 0; c < 6; ++c) sA[c][t] += sA[c][t + off];
        }
        __syncthreads();
    }
    const float inv = 1.f / 2048.f;
    float mi = sA[0][0] * inv, ri = rsqrtf(sA[1][0] * inv - mi * mi + EPSF);
    float mo = sA[2][0] * inv, ro = rsqrtf(sA[3][0] * inv - mo * mo + EPSF);
    float mu = sA[4][0] * inv, ru = rsqrtf(sA[5][0] * inv - mu * mu + EPSF);
    __syncthreads();

    float o_[8], v_[8];
    float sv = 0, qv = 0;
    #pragma unroll
    for (int i = 0; i < 8; ++i) {
        int h = t * 8 + i;
        float ivl = 1.f / (1.f + expf(-((vi[i] - mi) * ri * gi[h] + bi[h])));
        o_[i]     = 1.f / (1.f + expf(-((vo[i] - mo) * ro * go[h] + bo[h])));
        float uvl = tanhf((vu[i] - mu) * ru * gu[h] + bu[h]);
        v_[i] = ivl * uvl + fc[h];
        sv += v_[i]; qv += v_[i] * v_[i];
    }
    sA[0][t] = sv; sA[1][t] = qv;
    __syncthreads();
    for (int off = 128; off; off >>= 1) {
        if (t < off) { sA[0][t] += sA[0][t + off]; sA[1][t] += sA[1][t + off]; }
        __syncthreads();
    }
    float mc = sA[0][0] * inv, rc = rsqrtf(sA[1][0] * inv - mc * mc + EPSF);
    #pragma unroll
    for (int i = 0; i < 8; ++i) {
        int h = t * 8 + i;
        float nc = (v_[i] - mc) * rc * gc[h] + bc[h];
        float nh = o_[i] * tanhf(nc);
        out[h]        = nh;   // new_h
        out[2048 + h] = nc;   // new_cell
    }
}

// ---------------------------------------------------------------------------
extern "C" void kernel_launch(void* const* d_in, const int* in_sizes, int n_in,
                              void* d_out, int out_size, void* d_ws, size_t ws_size,
                              hipStream_t stream)
{
    const float* input    = (const float*)d_in[0];   // [2048]
    const float* hiddens  = (const float*)d_in[1];   // [32,2048]
    const float* cells    = (const float*)d_in[2];   // [32,2048]
    const float* external = (const float*)d_in[3];   // [2048]
    const float* W_ai     = (const float*)d_in[4];   // [2048,4096]
    const float* W_attn   = (const float*)d_in[5];   // [1,2048]
    const float* W_merge  = (const float*)d_in[6];   // [2048,2048]
    const float* W_iou    = (const float*)d_in[7];   // [6144,4096]
    const float* W_fi     = (const float*)d_in[8];   // [2048,2048]
    const float* W_fh     = (const float*)d_in[9];   // [2048,2048]
    const float* g_merge  = (const float*)d_in[10];
    const float* b_merge  = (const float*)d_in[11];
    const float* g_f      = (const float*)d_in[12];
    const float* b_f      = (const float*)d_in[13];
    const float* g_i      = (const float*)d_in[14];
    const float* b_i      = (const float*)d_in[15];
    const float* g_o      = (const float*)d_in[16];
    const float* b_o      = (const float*)d_in[17];
    const float* g_u      = (const float*)d_in[18];
    const float* b_u      = (const float*)d_in[19];
    const float* g_c      = (const float*)d_in[20];
    const float* b_c      = (const float*)d_in[21];

    float* ws = (float*)d_ws;
    float* ws_fh     = ws;              // 32*2048 = 65536
    float* ws_fi     = ws + 65536;      // 2048
    float* ws_lp     = ws + 67584;      // 128*32 = 4096
    float* ws_frs    = ws + 71680;      // 64
    float* ws_merged = ws + 71744;      // 2048
    float* ws_mm     = ws + 73792;      // 2048
    float* ws_fc     = ws + 75840;      // 2048
    float* ws_iou    = ws + 77888;      // 6144
    float* out = (float*)d_out;

    s1_mega<<<640, 256, 0, stream>>>(hiddens, external, input,
                                     W_ai, W_fh, W_fi, W_attn,
                                     ws_lp, ws_fh, ws_fi);
    s2_mega<<<40, 256, 0, stream>>>(ws_fi, ws_fh, ws_lp, hiddens,
                                    ws_frs, ws_merged);
    s3_mega<<<520, 256, 0, stream>>>(W_merge, ws_merged, ws_fi, ws_fh,
                                     ws_frs, g_f, b_f, cells, ws_mm, ws_fc);
    s4_iou<<<384, 256, 0, stream>>>(W_iou, ws_mm, input, g_merge, b_merge, ws_iou);
    s5_tail<<<1, 256, 0, stream>>>(ws_iou, ws_fc, g_i, b_i, g_o, b_o,
                                   g_u, b_u, g_c, b_c, out);
}